// Round 12
// baseline (201.970 us; speedup 1.0000x reference)
//
#include <hip/hip_runtime.h>
#include <math.h>

namespace {

typedef unsigned short u16;
typedef unsigned int   u32;
typedef __bf16 bf16x8 __attribute__((ext_vector_type(8)));
typedef float  f32x4  __attribute__((ext_vector_type(4)));
typedef float  f32x16 __attribute__((ext_vector_type(16)));
typedef u32    u32x4  __attribute__((ext_vector_type(4)));

// ---- workspace layout (u16 element offsets) --------------------------------
constexpr size_t OFF_XH  = 0;          // [4096][1024] bf16 hi of X (dead after proj)
constexpr size_t OFF_WH  = 4194304;    // [3072 j=qkv*1024+h*64+k'][1024 d] hi
constexpr size_t OFF_WL  = 7340032;    //                                   lo
constexpr size_t OFF_QH  = 10485760;   // [32 bh][2048][64]
constexpr size_t OFF_QL  = 14680064;   // [32 bh][2048][64]
constexpr size_t OFF_KH  = 18874368;   // [32 bh][2048][64]
constexpr size_t OFF_VT  = 23068672;   // [32 bh][64][2048]
constexpr size_t OFF_WOT = 27262976;   // [1024 d'][1024 c]
constexpr size_t OFF_L   = 28311552;   // f32[65536] raw column sums (131072 u16)
constexpr size_t OFF_AVH = 0;          // aliases XH (dead after proj)
// end = 28,442,624 u16 = 56.9 MB  (< 65.3 MB proven safe)

constexpr size_t VT_ELEMS = (size_t)32 * 64 * 2048;       // 4,194,304

__device__ __forceinline__ u16 f2bf(float x) {            // RNE fp32 -> bf16
  union { float f; unsigned u; } v; v.f = x;
  unsigned r = v.u + 0x7FFFu + ((v.u >> 16) & 1u);
  return (u16)(r >> 16);
}
__device__ __forceinline__ float bf2f(u16 b) {
  union { unsigned u; float f; } v; v.u = (unsigned)b << 16; return v.f;
}
__device__ __forceinline__ bf16x8 frag(const u16* p) {
  return *reinterpret_cast<const bf16x8*>(p);
}
__device__ __forceinline__ f32x4 mfma16(bf16x8 a, bf16x8 b, f32x4 c) {
  return __builtin_amdgcn_mfma_f32_16x16x32_bf16(a, b, c, 0, 0, 0);
}
__device__ __forceinline__ f32x16 mfma32(bf16x8 a, bf16x8 b, f32x16 c) {
  return __builtin_amdgcn_mfma_f32_32x32x16_bf16(a, b, c, 0, 0, 0);
}
__device__ __forceinline__ void gload16(const void* g, void* l) {
  __builtin_amdgcn_global_load_lds(
      (const __attribute__((address_space(1))) u32*)g,
      (__attribute__((address_space(3))) u32*)l, 16, 0, 0);
}
__device__ __forceinline__ u32 cvtpk(float lo, float hi) {
  u32 r;
  asm("v_cvt_pk_bf16_f32 %0, %1, %2" : "=v"(r) : "v"(lo), "v"(hi));
  return r;
}
__device__ __forceinline__ void pswap(u32& a, u32& b) {
  asm("v_permlane32_swap_b32 %0, %1" : "+v"(a), "+v"(b));
}

// ---------------------------------------------------------------------------
// Prep X: X f32 -> Xh bf16 (hi only); blocks <64 also zero the L accumulator.
// ---------------------------------------------------------------------------
__global__ __launch_bounds__(256) void k_prep_x(
    const float* __restrict__ X, u16* __restrict__ wsu)
{
  u16* Xh = wsu + OFF_XH;
  const size_t i = ((size_t)blockIdx.x * 256 + threadIdx.x) * 4;  // 4096 blocks
  const float4 v = *(const float4*)&X[i];
  ushort4 hh;
  hh.x = f2bf(v.x); hh.y = f2bf(v.y); hh.z = f2bf(v.z); hh.w = f2bf(v.w);
  *(ushort4*)&Xh[i] = hh;
  if (blockIdx.x < 64) {                       // zero L: 64*256*4 = 65536 f32
    float* L = (float*)(wsu + OFF_L);
    const size_t li = ((size_t)blockIdx.x * 256 + threadIdx.x) * 4;
    *(float4*)&L[li] = make_float4(0.f, 0.f, 0.f, 0.f);
  }
}

// ---------------------------------------------------------------------------
// Prep weights: bx<768 -> transpose+hi/lo split W_{q,k,v} into WALL[j][d];
// bx>=768 -> transpose W_O into WOT[d'][c].
// ---------------------------------------------------------------------------
__global__ __launch_bounds__(256) void k_prep_w(
    const float* __restrict__ Wq, const float* __restrict__ Wk,
    const float* __restrict__ Wv, const float* __restrict__ Wo,
    u16* __restrict__ wsu)
{
  const int bx = blockIdx.x;                 // 1024
  const int tid = threadIdx.x;
  __shared__ float T[64][65];
  if (bx < 768) {                            // 768 = qkv(3)*h(16)*dchunk(16)
    const int qkv = bx >> 8, h = (bx >> 4) & 15, dc = bx & 15;
    const float* W = qkv == 0 ? Wq : qkv == 1 ? Wk : Wv;
    const int d0 = dc * 64;
    for (int l = 0; l < 16; ++l) {
      int idx = tid + l * 256; int r = idx >> 6, c = idx & 63;  // r=d, c=k'
      T[r][c] = W[((size_t)h * 1024 + d0 + r) * 64 + c];
    }
    __syncthreads();
    u16* Wh = wsu + OFF_WH;
    u16* Wl = wsu + OFF_WL;
    for (int l = 0; l < 16; ++l) {
      int idx = tid + l * 256; int r = idx >> 6, c = idx & 63;  // r=k', c=d
      float v = T[c][r];
      u16 hi = f2bf(v);
      size_t o = (size_t)((qkv * 16 + h) * 64 + r) * 1024 + d0 + c;
      Wh[o] = hi;
      Wl[o] = f2bf(v - bf2f(hi));
    }
  } else {                                   // 256 = cchunk(16)*dchunk(16)
    const int b2 = bx - 768;
    const int c0 = (b2 >> 4) * 64, dd0 = (b2 & 15) * 64;
    for (int l = 0; l < 16; ++l) {
      int idx = tid + l * 256; int r = idx >> 6, c = idx & 63;
      T[r][c] = Wo[(size_t)(c0 + r) * 1024 + dd0 + c];
    }
    __syncthreads();
    u16* WOT = wsu + OFF_WOT;
    for (int l = 0; l < 16; ++l) {
      int idx = tid + l * 256; int r = idx >> 6, c = idx & 63;
      WOT[(size_t)(dd0 + r) * 1024 + c0 + c] = f2bf(T[c][r]);
    }
  }
}

// ---------------------------------------------------------------------------
// Fused QKV projection: C[4096][3072] = Xh . (Wh+Wl), 2-term split expressed
// as a K'=2048 GEMM (k-tile t: d0=(t>>1)*64, plane=t&1).  128x128 tile,
// SINGLE-buffered m97 2-barrier loop (32 KB LDS -> 4-5 blocks/CU; m132 showed
// the 64 KB dbuf's occupancy cut costs more than the overlap gains),
// XOR-swizzled LDS (conflict-free ds_read_b128, verified R11: conflicts = 0).
// Grid 768 = 8 XCD x (3 ct x 32 mt), column-ownership XCD swizzle.
// ---------------------------------------------------------------------------
__global__ __launch_bounds__(256, 2) void k_projg(u16* __restrict__ wsu)
{
  const int bid = blockIdx.x;                // 768
  const int xcd = bid & 7, local = bid >> 3; // local 0..95
  const int ct = xcd * 3 + local % 3;        // 24 col-tiles of 128
  const int mt = local / 3;                  // 32 row-tiles of 128
  const int gm0 = mt * 128;
  const int j0 = ct * 128;                   // row in WALL
  const int qkv = ct >> 3;

  const u16* XH = wsu + OFF_XH;
  const u16* WH = wsu + OFF_WH;
  const u16* WL = wsu + OFF_WL;

  __shared__ __align__(16) u16 lds[16384];   // A 128x64 | B 128x64  (32 KB)

  const int tid = threadIdx.x;
  const int w = tid >> 6, l = tid & 63, lr = l & 15, lg = l >> 4;
  const int wm = w >> 1, wn = w & 1;

  const f32x4 fz = {0.f, 0.f, 0.f, 0.f};
  f32x4 acc[4][4];
  for (int i = 0; i < 4; ++i) for (int j = 0; j < 4; ++j) acc[i][j] = fz;

  for (int t = 0; t < 32; ++t) {
    const int d0 = (t >> 1) * 64;
    const u16* Wp = (t & 1) ? WL : WH;
    __syncthreads();                         // prev-tile readers done
    #pragma unroll
    for (int it = 0; it < 8; ++it) {
      const int c = tid + it * 256;          // 0..2047 16B chunks
      const u16* src;
      if (c < 1024) {                        // A: X rows gm0..+127
        const int r = c >> 3, cl = c & 7;
        src = XH + (size_t)(gm0 + r) * 1024 + d0 + (cl ^ (r & 7)) * 8;
      } else {                               // B: W rows j0..+127 (this plane)
        const int cc = c - 1024;
        const int r = cc >> 3, cl = cc & 7;
        src = Wp + (size_t)(j0 + r) * 1024 + d0 + (cl ^ (r & 7)) * 8;
      }
      gload16(src, lds + (size_t)c * 8);
    }
    __syncthreads();                         // loads landed (vmcnt drain)

    const u16* As = lds;
    const u16* Bs = lds + 8192;
    #pragma unroll
    for (int ks = 0; ks < 2; ++ks) {
      bf16x8 a[4], b[4];
      #pragma unroll
      for (int mf = 0; mf < 4; ++mf) {
        const int row = wm * 64 + mf * 16 + lr;
        a[mf] = frag(As + row * 64 + ((ks * 4 + lg) ^ (row & 7)) * 8);
      }
      #pragma unroll
      for (int nf = 0; nf < 4; ++nf) {
        const int row = wn * 64 + nf * 16 + lr;
        b[nf] = frag(Bs + row * 64 + ((ks * 4 + lg) ^ (row & 7)) * 8);
      }
      #pragma unroll
      for (int nf = 0; nf < 4; ++nf)
        #pragma unroll
        for (int mf = 0; mf < 4; ++mf)
          acc[mf][nf] = mfma16(a[mf], b[nf], acc[mf][nf]);
    }
  }

  const int colbase = j0 + wn * 64;          // this wave's 64 cols = ONE head
  const int h = (colbase >> 6) & 15;
  if (qkv == 0) {        // Q: hi/lo planes [bh][n][64]
    u16* Ph = wsu + OFF_QH;
    u16* Pl = wsu + OFF_QL;
    #pragma unroll
    for (int mf = 0; mf < 4; ++mf)
      #pragma unroll
      for (int nf = 0; nf < 4; ++nf)
        #pragma unroll
        for (int r = 0; r < 4; ++r) {
          const float v = acc[mf][nf][r];
          const int gn = gm0 + wm * 64 + mf * 16 + lg * 4 + r;
          const int b = gn >> 11, n = gn & 2047;
          const int kp = nf * 16 + lr;
          const size_t o = ((size_t)(b * 16 + h) * 2048 + n) * 64 + kp;
          const u16 hi = f2bf(v);
          Ph[o] = hi;
          Pl[o] = f2bf(v - bf2f(hi));
        }
  } else if (qkv == 1) { // K: hi only
    u16* Ph = wsu + OFF_KH;
    #pragma unroll
    for (int mf = 0; mf < 4; ++mf)
      #pragma unroll
      for (int nf = 0; nf < 4; ++nf)
        #pragma unroll
        for (int r = 0; r < 4; ++r) {
          const int gn = gm0 + wm * 64 + mf * 16 + lg * 4 + r;
          const int b = gn >> 11, n = gn & 2047;
          const int kp = nf * 16 + lr;
          Ph[((size_t)(b * 16 + h) * 2048 + n) * 64 + kp] = f2bf(acc[mf][nf][r]);
        }
  } else {               // V: transposed store VT[bh][k'][n]
    u16* VT = wsu + OFF_VT;
    #pragma unroll
    for (int mf = 0; mf < 4; ++mf)
      #pragma unroll
      for (int nf = 0; nf < 4; ++nf) {
        const int gn = gm0 + wm * 64 + mf * 16 + lg * 4;
        const int b = gn >> 11, n = gn & 2047;
        const int kp = nf * 16 + lr;
        ushort4 p;
        p.x = f2bf(acc[mf][nf][0]); p.y = f2bf(acc[mf][nf][1]);
        p.z = f2bf(acc[mf][nf][2]); p.w = f2bf(acc[mf][nf][3]);
        *(ushort4*)&VT[((size_t)(b * 16 + h) * 64 + kp) * 2048 + n] = p;
      }
  }
}

// ---------------------------------------------------------------------------
// Pass 1 (i-split x4, 2-TERM: l_j = sum_i exp(Kh_j . (Qh+Ql)_i)), atomicAdd.
// [round-11 verbatim]
// ---------------------------------------------------------------------------
__global__ __launch_bounds__(256, 2) void k_pass1(
    u16* __restrict__ wsu, float* __restrict__ L)
{
  const int bid = blockIdx.x;                    // 2048
  const int swz = (bid & 7) * 256 + (bid >> 3);
  const int bh = swz >> 6;
  const int jtile = (swz >> 2) & 15;
  const int isl = swz & 3;
  const int j0 = jtile * 128;
  const u16* Qh = wsu + OFF_QH + (size_t)bh * 131072;
  const u16* Ql = wsu + OFF_QL + (size_t)bh * 131072;
  const u16* Kh = wsu + OFF_KH + (size_t)bh * 131072;

  __shared__ __align__(16) u16 lds[2][2][4096];   // [buf][Qhi,Qlo][64][64]

  const int tid = threadIdx.x;
  const int w = tid >> 6, l = tid & 63;
  const int il = l & 31, hi = l >> 5;

  bf16x8 kah[4];                                 // stationary K A-frags
  {
    const int jrow = j0 + w * 32 + il;
    #pragma unroll
    for (int ks = 0; ks < 4; ++ks)
      kah[ks] = frag(&Kh[(size_t)jrow * 64 + ks * 16 + hi * 8]);
  }

  auto stage = [&](int buf, int ic) {
    const int i0 = ic * 64;
    #pragma unroll
    for (int it = 0; it < 4; ++it) {
      const int c = tid + it * 256;              // 0..1023
      const int plane = c >> 9, cc = c & 511;
      const int r = cc >> 3, cl = cc & 7;
      const int sw8 = (cl ^ (r & 7)) * 8;        // inverse-swizzled source
      const u16* src = (plane ? Ql : Qh) + (size_t)(i0 + r) * 64 + sw8;
      gload16(src, &lds[buf][0][0] + (size_t)c * 8);
    }
  };

  const f32x16 fz16 = {0,0,0,0,0,0,0,0,0,0,0,0,0,0,0,0};
  float lsum[16] = {};
  const int icbase = isl * 8;

  stage(0, icbase);
  __syncthreads();
  int cur = 0;
  for (int ii = 0; ii < 8; ++ii) {
    if (ii < 7) stage(cur ^ 1, icbase + ii + 1);
    const u16* Qsh = &lds[cur][0][0];
    const u16* Qsl = &lds[cur][1][0];
    #pragma unroll
    for (int it2 = 0; it2 < 2; ++it2) {
      f32x16 s = fz16;
      const int qrow = it2 * 32 + il;
      #pragma unroll
      for (int ks = 0; ks < 4; ++ks) {
        const int ch = ((ks * 2 + hi) ^ (qrow & 7)) * 8;   // swizzled read
        s = mfma32(kah[ks], frag(&Qsh[qrow * 64 + ch]), s);
        s = mfma32(kah[ks], frag(&Qsl[qrow * 64 + ch]), s);
      }
      #pragma unroll
      for (int r = 0; r < 16; ++r) lsum[r] += __expf(s[r]);
    }
    __syncthreads();
    cur ^= 1;
  }

  #pragma unroll
  for (int r = 0; r < 16; ++r) {
    float v = lsum[r];
    v += __shfl_xor(v, 1);  v += __shfl_xor(v, 2);
    v += __shfl_xor(v, 4);  v += __shfl_xor(v, 8);
    v += __shfl_xor(v, 16);
    if (il == 0) {
      const int j = j0 + w * 32 + (r & 3) + 8 * (r >> 2) + 4 * hi;
      atomicAdd(&L[(size_t)bh * 2048 + j], v);
    }
  }
}

// ---------------------------------------------------------------------------
// Scale V^T by 1/l along n:  VT[bh][c][n] *= rcp(L[bh][n])  [round-11 verbatim]
// ---------------------------------------------------------------------------
__global__ __launch_bounds__(256) void k_scale_v(
    u16* __restrict__ wsu, const float* __restrict__ L)
{
  u16* VT = wsu + OFF_VT;
  const size_t vid = (size_t)blockIdx.x * 256 + threadIdx.x;  // 0..524287
  if (vid * 8 >= VT_ELEMS) return;
  const size_t base = vid * 8;
  const int n8 = (int)(vid & 255);
  const int bh = (int)(vid >> 14);
  ushort4 a = *(ushort4*)&VT[base];
  ushort4 b = *(ushort4*)&VT[base + 4];
  const float* Lp = L + (size_t)bh * 2048 + n8 * 8;
  a.x = f2bf(bf2f(a.x) * __builtin_amdgcn_rcpf(Lp[0]));
  a.y = f2bf(bf2f(a.y) * __builtin_amdgcn_rcpf(Lp[1]));
  a.z = f2bf(bf2f(a.z) * __builtin_amdgcn_rcpf(Lp[2]));
  a.w = f2bf(bf2f(a.w) * __builtin_amdgcn_rcpf(Lp[3]));
  b.x = f2bf(bf2f(b.x) * __builtin_amdgcn_rcpf(Lp[4]));
  b.y = f2bf(bf2f(b.y) * __builtin_amdgcn_rcpf(Lp[5]));
  b.z = f2bf(bf2f(b.z) * __builtin_amdgcn_rcpf(Lp[6]));
  b.w = f2bf(bf2f(b.w) * __builtin_amdgcn_rcpf(Lp[7]));
  *(ushort4*)&VT[base] = a;
  *(ushort4*)&VT[base + 4] = b;
}

// ---------------------------------------------------------------------------
// Pass 2 (4-wave, 2-TERM S, in-register P): AV[i][c] = sum_j exp(S_ij) V'[j][c]
// [round-11 verbatim]
// ---------------------------------------------------------------------------
__global__ __launch_bounds__(256, 2) void k_pass2(u16* __restrict__ wsu)
{
  const int bid = blockIdx.x;                  // 512
  const int swz = (bid & 7) * 64 + (bid >> 3);
  const int itile = swz & 15, bh = swz >> 4;
  const int i0 = itile * 128;
  const u16* Qh = wsu + OFF_QH + (size_t)bh * 131072;
  const u16* Ql = wsu + OFF_QL + (size_t)bh * 131072;
  const u16* Kh = wsu + OFF_KH + (size_t)bh * 131072;
  const u16* VT = wsu + OFF_VT + (size_t)bh * 131072;

  __shared__ __align__(16) u16 lds[2][2][4096];  // [buf][Kh,V][64][64]

  const int tid = threadIdx.x;
  const int w = tid >> 6, l = tid & 63;
  const int il = l & 31, hi = l >> 5;

  bf16x8 qbh[4], qbl[4];                       // stationary Q B-frags
  {
    const int irow = i0 + w * 32 + il;
    #pragma unroll
    for (int ks = 0; ks < 4; ++ks) {
      const size_t o = (size_t)irow * 64 + ks * 16 + hi * 8;
      qbh[ks] = frag(&Qh[o]);
      qbl[ks] = frag(&Ql[o]);
    }
  }

  auto stage = [&](int buf, int jc) {
    const int j0 = jc * 64;
    #pragma unroll
    for (int it = 0; it < 4; ++it) {
      const int c = tid + it * 256;            // 0..1023
      const int plane = c >> 9, cc = c & 511;
      const int r = cc >> 3, cl = cc & 7;
      const int sw8 = (cl ^ (r & 7)) * 8;
      const u16* src = plane == 0 ? Kh + (size_t)(j0 + r) * 64 + sw8
                                  : VT + (size_t)r * 2048 + j0 + sw8;
      gload16(src, &lds[buf][0][0] + (size_t)c * 8);
    }
  };

  const f32x16 fz16 = {0,0,0,0,0,0,0,0,0,0,0,0,0,0,0,0};
  f32x16 acc[2]; acc[0] = fz16; acc[1] = fz16;

  stage(0, 0);
  __syncthreads();
  int cur = 0;
  for (int jc = 0; jc < 32; ++jc) {
    if (jc < 31) stage(cur ^ 1, jc + 1);
    const u16* Ksh = &lds[cur][0][0];
    const u16* Vs  = &lds[cur][1][0];
    #pragma unroll
    for (int jt = 0; jt < 2; ++jt) {
      f32x16 s = fz16;
      const int jrow = jt * 32 + il;
      #pragma unroll
      for (int ks = 0; ks < 4; ++ks) {
        const int ch = ((ks * 2 + hi) ^ (jrow & 7)) * 8;
        bf16x8 ka = frag(&Ksh[jrow * 64 + ch]);
        s = mfma32(ka, qbh[ks], s);
        s = mfma32(ka, qbl[ks], s);
      }
      float p[16];
      #pragma unroll
      for (int r = 0; r < 16; ++r) p[r] = __expf(s[r]);
      u32 a0 = cvtpk(p[0],  p[1]),  b0 = cvtpk(p[4],  p[5]);
      u32 a1 = cvtpk(p[2],  p[3]),  b1 = cvtpk(p[6],  p[7]);
      u32 a2 = cvtpk(p[8],  p[9]),  b2 = cvtpk(p[12], p[13]);
      u32 a3 = cvtpk(p[10], p[11]), b3 = cvtpk(p[14], p[15]);
      pswap(a0, b0); pswap(a1, b1); pswap(a2, b2); pswap(a3, b3);
      u32x4 pw0 = {a0, a1, b0, b1};            // k = j 0..15 of this jt
      u32x4 pw1 = {a2, a3, b2, b3};            // k = j 16..31
      bf16x8 pa0 = __builtin_bit_cast(bf16x8, pw0);
      bf16x8 pa1 = __builtin_bit_cast(bf16x8, pw1);
      #pragma unroll
      for (int cb = 0; cb < 2; ++cb) {
        const int crow = cb * 32 + il;
        const int c0 = ((jt * 4 + 0 + hi) ^ (crow & 7)) * 8;
        const int c1 = ((jt * 4 + 2 + hi) ^ (crow & 7)) * 8;
        bf16x8 vb0 = frag(&Vs[crow * 64 + c0]);
        bf16x8 vb1 = frag(&Vs[crow * 64 + c1]);
        acc[cb] = mfma32(pa0, vb0, acc[cb]);
        acc[cb] = mfma32(pa1, vb1, acc[cb]);
      }
    }
    __syncthreads();
    cur ^= 1;
  }

  u16* AVh = wsu + OFF_AVH;                    // hi only (1-term outproj)
  #pragma unroll
  for (int cb = 0; cb < 2; ++cb)
    #pragma unroll
    for (int r = 0; r < 16; ++r) {
      const int iloc = (r & 3) + 8 * (r >> 2) + 4 * hi;
      const int g = i0 + w * 32 + iloc;
      const int c = cb * 32 + il;
      AVh[((size_t)bh * 2048 + g) * 64 + c] = f2bf(acc[cb][r]);
    }
}

// ---------------------------------------------------------------------------
// Output projection: Out = AVh[4096][1024] . WO  (1-term)
// SINGLE-buffered m97 2-barrier loop + XOR-swizzled LDS (same as projg).
// ---------------------------------------------------------------------------
__global__ __launch_bounds__(256, 2) void k_outproj(
    const u16* __restrict__ wsu, float* __restrict__ Out)
{
  const int bx = blockIdx.x;                 // 256 = gm(32) * dn(8)
  const int gm = bx >> 3, dn = bx & 7;       // dn == bid&7: per-XCD WOT strip
  const int g0 = gm * 128, d0 = dn * 128;
  const u16* AVh = wsu + OFF_AVH;
  const u16* WOT = wsu + OFF_WOT;

  __shared__ __align__(16) u16 lds[16384];   // A 128x64 | B 128x64  (32 KB)

  const int tid = threadIdx.x;
  const int w = tid >> 6, l = tid & 63, lr = l & 15, lg = l >> 4;
  const int wm = w >> 1, wn = w & 1;

  const f32x4 fz = {0.f, 0.f, 0.f, 0.f};
  f32x4 acc[4][4];
  for (int i = 0; i < 4; ++i) for (int j = 0; j < 4; ++j) acc[i][j] = fz;

  for (int t = 0; t < 16; ++t) {
    const int c0 = t * 64;
    __syncthreads();
    #pragma unroll
    for (int it = 0; it < 8; ++it) {
      const int c = tid + it * 256;          // 0..2047 16B chunks
      const u16* src;
      if (c < 1024) {                        // A: AVh rows g0..+127
        const int r = c >> 3, cl = c & 7;
        src = AVh + (size_t)(g0 + r) * 1024 + c0 + (cl ^ (r & 7)) * 8;
      } else {                               // B: WOT rows d0..+127
        const int cc = c - 1024;
        const int r = cc >> 3, cl = cc & 7;
        src = WOT + (size_t)(d0 + r) * 1024 + c0 + (cl ^ (r & 7)) * 8;
      }
      gload16(src, lds + (size_t)c * 8);
    }
    __syncthreads();

    const u16* As = lds;
    const u16* Bs = lds + 8192;
    #pragma unroll
    for (int ks = 0; ks < 2; ++ks) {
      bf16x8 a[4], b[4];
      #pragma unroll
      for (int mf = 0; mf < 4; ++mf) {
        const int row = wm * 64 + mf * 16 + lr;
        a[mf] = frag(As + row * 64 + ((ks * 4 + lg) ^ (row & 7)) * 8);
      }
      #pragma unroll
      for (int nf = 0; nf < 4; ++nf) {
        const int row = wn * 64 + nf * 16 + lr;
        b[nf] = frag(Bs + row * 64 + ((ks * 4 + lg) ^ (row & 7)) * 8);
      }
      #pragma unroll
      for (int nf = 0; nf < 4; ++nf)
        #pragma unroll
        for (int mf = 0; mf < 4; ++mf)
          acc[mf][nf] = mfma16(a[mf], b[nf], acc[mf][nf]);
    }
  }
  #pragma unroll
  for (int mf = 0; mf < 4; ++mf)
    #pragma unroll
    for (int nf = 0; nf < 4; ++nf)
      #pragma unroll
      for (int r = 0; r < 4; ++r) {
        const int g = g0 + wm * 64 + mf * 16 + lg * 4 + r;
        const int d = d0 + wn * 64 + nf * 16 + lr;
        Out[(size_t)g * 1024 + d] = acc[mf][nf][r];
      }
}

} // anonymous namespace

extern "C" void kernel_launch(void* const* d_in, const int* in_sizes, int n_in,
                              void* d_out, int out_size, void* d_ws, size_t ws_size,
                              hipStream_t stream) {
  const float* X  = (const float*)d_in[0];
  const float* Wq = (const float*)d_in[1];
  const float* Wk = (const float*)d_in[2];
  const float* Wv = (const float*)d_in[3];
  const float* Wo = (const float*)d_in[4];
  float* out = (float*)d_out;
  u16* wsu = (u16*)d_ws;
  float* L = (float*)(wsu + OFF_L);

  k_prep_x  <<<4096, 256, 0, stream>>>(X, wsu);
  k_prep_w  <<<1024, 256, 0, stream>>>(Wq, Wk, Wv, Wo, wsu);
  k_projg   <<<768,  256, 0, stream>>>(wsu);
  k_pass1   <<<2048, 256, 0, stream>>>(wsu, L);
  k_scale_v <<<2048, 256, 0, stream>>>(wsu, L);
  k_pass2   <<<512,  256, 0, stream>>>(wsu);
  k_outproj <<<256,  256, 0, stream>>>(wsu, out);
}

// Round 13
// 197.719 us; speedup vs baseline: 1.0215x; 1.0215x over previous
//
#include <hip/hip_runtime.h>
#include <math.h>

namespace {

typedef unsigned short u16;
typedef unsigned int   u32;
typedef __bf16 bf16x8 __attribute__((ext_vector_type(8)));
typedef float  f32x4  __attribute__((ext_vector_type(4)));
typedef float  f32x16 __attribute__((ext_vector_type(16)));
typedef u32    u32x4  __attribute__((ext_vector_type(4)));

// ---- workspace layout (u16 element offsets) --------------------------------
constexpr size_t OFF_XH  = 0;          // [4096][1024] bf16 hi of X (dead after proj)
constexpr size_t OFF_WH  = 4194304;    // [3072 j=qkv*1024+h*64+k'][1024 d] hi
constexpr size_t OFF_WL  = 7340032;    //                                   lo
constexpr size_t OFF_QH  = 10485760;   // [32 bh][2048][64]
constexpr size_t OFF_QL  = 14680064;   // [32 bh][2048][64]
constexpr size_t OFF_KH  = 18874368;   // [32 bh][2048][64]
constexpr size_t OFF_VT  = 23068672;   // [32 bh][64][2048]
constexpr size_t OFF_WOT = 27262976;   // [1024 d'][1024 c]
constexpr size_t OFF_L   = 28311552;   // f32[65536] raw column sums (131072 u16)
constexpr size_t OFF_AVH = 0;          // aliases XH (dead after proj)
// end = 28,442,624 u16 = 56.9 MB  (< 65.3 MB proven safe)

constexpr size_t VT_ELEMS = (size_t)32 * 64 * 2048;       // 4,194,304

__device__ __forceinline__ u16 f2bf(float x) {            // RNE fp32 -> bf16
  union { float f; unsigned u; } v; v.f = x;
  unsigned r = v.u + 0x7FFFu + ((v.u >> 16) & 1u);
  return (u16)(r >> 16);
}
__device__ __forceinline__ float bf2f(u16 b) {
  union { unsigned u; float f; } v; v.u = (unsigned)b << 16; return v.f;
}
__device__ __forceinline__ bf16x8 frag(const u16* p) {
  return *reinterpret_cast<const bf16x8*>(p);
}
__device__ __forceinline__ f32x4 mfma16(bf16x8 a, bf16x8 b, f32x4 c) {
  return __builtin_amdgcn_mfma_f32_16x16x32_bf16(a, b, c, 0, 0, 0);
}
__device__ __forceinline__ f32x16 mfma32(bf16x8 a, bf16x8 b, f32x16 c) {
  return __builtin_amdgcn_mfma_f32_32x32x16_bf16(a, b, c, 0, 0, 0);
}
__device__ __forceinline__ void gload16(const void* g, void* l) {
  __builtin_amdgcn_global_load_lds(
      (const __attribute__((address_space(1))) u32*)g,
      (__attribute__((address_space(3))) u32*)l, 16, 0, 0);
}
__device__ __forceinline__ u32 cvtpk(float lo, float hi) {
  u32 r;
  asm("v_cvt_pk_bf16_f32 %0, %1, %2" : "=v"(r) : "v"(lo), "v"(hi));
  return r;
}
__device__ __forceinline__ void pswap(u32& a, u32& b) {
  asm("v_permlane32_swap_b32 %0, %1" : "+v"(a), "+v"(b));
}

// ---------------------------------------------------------------------------
// Prep X: X f32 -> Xh bf16 (hi only); blocks <64 also zero the L accumulator.
// ---------------------------------------------------------------------------
__global__ __launch_bounds__(256) void k_prep_x(
    const float* __restrict__ X, u16* __restrict__ wsu)
{
  u16* Xh = wsu + OFF_XH;
  const size_t i = ((size_t)blockIdx.x * 256 + threadIdx.x) * 4;  // 4096 blocks
  const float4 v = *(const float4*)&X[i];
  ushort4 hh;
  hh.x = f2bf(v.x); hh.y = f2bf(v.y); hh.z = f2bf(v.z); hh.w = f2bf(v.w);
  *(ushort4*)&Xh[i] = hh;
  if (blockIdx.x < 64) {                       // zero L: 64*256*4 = 65536 f32
    float* L = (float*)(wsu + OFF_L);
    const size_t li = ((size_t)blockIdx.x * 256 + threadIdx.x) * 4;
    *(float4*)&L[li] = make_float4(0.f, 0.f, 0.f, 0.f);
  }
}

// ---------------------------------------------------------------------------
// Prep weights: bx<768 -> transpose+hi/lo split W_{q,k,v} into WALL[j][d];
// bx>=768 -> transpose W_O into WOT[d'][c].
// ---------------------------------------------------------------------------
__global__ __launch_bounds__(256) void k_prep_w(
    const float* __restrict__ Wq, const float* __restrict__ Wk,
    const float* __restrict__ Wv, const float* __restrict__ Wo,
    u16* __restrict__ wsu)
{
  const int bx = blockIdx.x;                 // 1024
  const int tid = threadIdx.x;
  __shared__ float T[64][65];
  if (bx < 768) {                            // 768 = qkv(3)*h(16)*dchunk(16)
    const int qkv = bx >> 8, h = (bx >> 4) & 15, dc = bx & 15;
    const float* W = qkv == 0 ? Wq : qkv == 1 ? Wk : Wv;
    const int d0 = dc * 64;
    for (int l = 0; l < 16; ++l) {
      int idx = tid + l * 256; int r = idx >> 6, c = idx & 63;  // r=d, c=k'
      T[r][c] = W[((size_t)h * 1024 + d0 + r) * 64 + c];
    }
    __syncthreads();
    u16* Wh = wsu + OFF_WH;
    u16* Wl = wsu + OFF_WL;
    for (int l = 0; l < 16; ++l) {
      int idx = tid + l * 256; int r = idx >> 6, c = idx & 63;  // r=k', c=d
      float v = T[c][r];
      u16 hi = f2bf(v);
      size_t o = (size_t)((qkv * 16 + h) * 64 + r) * 1024 + d0 + c;
      Wh[o] = hi;
      Wl[o] = f2bf(v - bf2f(hi));
    }
  } else {                                   // 256 = cchunk(16)*dchunk(16)
    const int b2 = bx - 768;
    const int c0 = (b2 >> 4) * 64, dd0 = (b2 & 15) * 64;
    for (int l = 0; l < 16; ++l) {
      int idx = tid + l * 256; int r = idx >> 6, c = idx & 63;
      T[r][c] = Wo[(size_t)(c0 + r) * 1024 + dd0 + c];
    }
    __syncthreads();
    u16* WOT = wsu + OFF_WOT;
    for (int l = 0; l < 16; ++l) {
      int idx = tid + l * 256; int r = idx >> 6, c = idx & 63;
      WOT[(size_t)(dd0 + r) * 1024 + c0 + c] = f2bf(T[c][r]);
    }
  }
}

// ---------------------------------------------------------------------------
// Fused QKV projection: C[4096][3072] = Xh . (Wh+Wl), 2-term split expressed
// as a K'=2048 GEMM (k-tile t: d0=(t>>1)*64, plane=t&1).  128x128 tile,
// SINGLE-buffered m97 2-barrier loop (32 KB LDS -> ~4 blocks/CU; validated
// R12: 66 us, conflicts 0, Occ 24%), XOR-swizzled LDS.
// Grid 768 = 8 XCD x (3 ct x 32 mt), column-ownership XCD swizzle.
// ---------------------------------------------------------------------------
__global__ __launch_bounds__(256, 2) void k_projg(u16* __restrict__ wsu)
{
  const int bid = blockIdx.x;                // 768
  const int xcd = bid & 7, local = bid >> 3; // local 0..95
  const int ct = xcd * 3 + local % 3;        // 24 col-tiles of 128
  const int mt = local / 3;                  // 32 row-tiles of 128
  const int gm0 = mt * 128;
  const int j0 = ct * 128;                   // row in WALL
  const int qkv = ct >> 3;

  const u16* XH = wsu + OFF_XH;
  const u16* WH = wsu + OFF_WH;
  const u16* WL = wsu + OFF_WL;

  __shared__ __align__(16) u16 lds[16384];   // A 128x64 | B 128x64  (32 KB)

  const int tid = threadIdx.x;
  const int w = tid >> 6, l = tid & 63, lr = l & 15, lg = l >> 4;
  const int wm = w >> 1, wn = w & 1;

  const f32x4 fz = {0.f, 0.f, 0.f, 0.f};
  f32x4 acc[4][4];
  for (int i = 0; i < 4; ++i) for (int j = 0; j < 4; ++j) acc[i][j] = fz;

  for (int t = 0; t < 32; ++t) {
    const int d0 = (t >> 1) * 64;
    const u16* Wp = (t & 1) ? WL : WH;
    __syncthreads();                         // prev-tile readers done
    #pragma unroll
    for (int it = 0; it < 8; ++it) {
      const int c = tid + it * 256;          // 0..2047 16B chunks
      const u16* src;
      if (c < 1024) {                        // A: X rows gm0..+127
        const int r = c >> 3, cl = c & 7;
        src = XH + (size_t)(gm0 + r) * 1024 + d0 + (cl ^ (r & 7)) * 8;
      } else {                               // B: W rows j0..+127 (this plane)
        const int cc = c - 1024;
        const int r = cc >> 3, cl = cc & 7;
        src = Wp + (size_t)(j0 + r) * 1024 + d0 + (cl ^ (r & 7)) * 8;
      }
      gload16(src, lds + (size_t)c * 8);
    }
    __syncthreads();                         // loads landed (vmcnt drain)

    const u16* As = lds;
    const u16* Bs = lds + 8192;
    #pragma unroll
    for (int ks = 0; ks < 2; ++ks) {
      bf16x8 a[4], b[4];
      #pragma unroll
      for (int mf = 0; mf < 4; ++mf) {
        const int row = wm * 64 + mf * 16 + lr;
        a[mf] = frag(As + row * 64 + ((ks * 4 + lg) ^ (row & 7)) * 8);
      }
      #pragma unroll
      for (int nf = 0; nf < 4; ++nf) {
        const int row = wn * 64 + nf * 16 + lr;
        b[nf] = frag(Bs + row * 64 + ((ks * 4 + lg) ^ (row & 7)) * 8);
      }
      #pragma unroll
      for (int nf = 0; nf < 4; ++nf)
        #pragma unroll
        for (int mf = 0; mf < 4; ++mf)
          acc[mf][nf] = mfma16(a[mf], b[nf], acc[mf][nf]);
    }
  }

  const int colbase = j0 + wn * 64;          // this wave's 64 cols = ONE head
  const int h = (colbase >> 6) & 15;
  if (qkv == 0) {        // Q: hi/lo planes [bh][n][64]
    u16* Ph = wsu + OFF_QH;
    u16* Pl = wsu + OFF_QL;
    #pragma unroll
    for (int mf = 0; mf < 4; ++mf)
      #pragma unroll
      for (int nf = 0; nf < 4; ++nf)
        #pragma unroll
        for (int r = 0; r < 4; ++r) {
          const float v = acc[mf][nf][r];
          const int gn = gm0 + wm * 64 + mf * 16 + lg * 4 + r;
          const int b = gn >> 11, n = gn & 2047;
          const int kp = nf * 16 + lr;
          const size_t o = ((size_t)(b * 16 + h) * 2048 + n) * 64 + kp;
          const u16 hi = f2bf(v);
          Ph[o] = hi;
          Pl[o] = f2bf(v - bf2f(hi));
        }
  } else if (qkv == 1) { // K: hi only
    u16* Ph = wsu + OFF_KH;
    #pragma unroll
    for (int mf = 0; mf < 4; ++mf)
      #pragma unroll
      for (int nf = 0; nf < 4; ++nf)
        #pragma unroll
        for (int r = 0; r < 4; ++r) {
          const int gn = gm0 + wm * 64 + mf * 16 + lg * 4 + r;
          const int b = gn >> 11, n = gn & 2047;
          const int kp = nf * 16 + lr;
          Ph[((size_t)(b * 16 + h) * 2048 + n) * 64 + kp] = f2bf(acc[mf][nf][r]);
        }
  } else {               // V: transposed store VT[bh][k'][n]
    u16* VT = wsu + OFF_VT;
    #pragma unroll
    for (int mf = 0; mf < 4; ++mf)
      #pragma unroll
      for (int nf = 0; nf < 4; ++nf) {
        const int gn = gm0 + wm * 64 + mf * 16 + lg * 4;
        const int b = gn >> 11, n = gn & 2047;
        const int kp = nf * 16 + lr;
        ushort4 p;
        p.x = f2bf(acc[mf][nf][0]); p.y = f2bf(acc[mf][nf][1]);
        p.z = f2bf(acc[mf][nf][2]); p.w = f2bf(acc[mf][nf][3]);
        *(ushort4*)&VT[((size_t)(b * 16 + h) * 64 + kp) * 2048 + n] = p;
      }
  }
}

// ---------------------------------------------------------------------------
// Pass 1 (i-split x4, 2-TERM: l_j = sum_i exp(Kh_j . (Qh+Ql)_i)), atomicAdd.
// [round-12 verbatim]
// ---------------------------------------------------------------------------
__global__ __launch_bounds__(256, 2) void k_pass1(
    u16* __restrict__ wsu, float* __restrict__ L)
{
  const int bid = blockIdx.x;                    // 2048
  const int swz = (bid & 7) * 256 + (bid >> 3);
  const int bh = swz >> 6;
  const int jtile = (swz >> 2) & 15;
  const int isl = swz & 3;
  const int j0 = jtile * 128;
  const u16* Qh = wsu + OFF_QH + (size_t)bh * 131072;
  const u16* Ql = wsu + OFF_QL + (size_t)bh * 131072;
  const u16* Kh = wsu + OFF_KH + (size_t)bh * 131072;

  __shared__ __align__(16) u16 lds[2][2][4096];   // [buf][Qhi,Qlo][64][64]

  const int tid = threadIdx.x;
  const int w = tid >> 6, l = tid & 63;
  const int il = l & 31, hi = l >> 5;

  bf16x8 kah[4];                                 // stationary K A-frags
  {
    const int jrow = j0 + w * 32 + il;
    #pragma unroll
    for (int ks = 0; ks < 4; ++ks)
      kah[ks] = frag(&Kh[(size_t)jrow * 64 + ks * 16 + hi * 8]);
  }

  auto stage = [&](int buf, int ic) {
    const int i0 = ic * 64;
    #pragma unroll
    for (int it = 0; it < 4; ++it) {
      const int c = tid + it * 256;              // 0..1023
      const int plane = c >> 9, cc = c & 511;
      const int r = cc >> 3, cl = cc & 7;
      const int sw8 = (cl ^ (r & 7)) * 8;        // inverse-swizzled source
      const u16* src = (plane ? Ql : Qh) + (size_t)(i0 + r) * 64 + sw8;
      gload16(src, &lds[buf][0][0] + (size_t)c * 8);
    }
  };

  const f32x16 fz16 = {0,0,0,0,0,0,0,0,0,0,0,0,0,0,0,0};
  float lsum[16] = {};
  const int icbase = isl * 8;

  stage(0, icbase);
  __syncthreads();
  int cur = 0;
  for (int ii = 0; ii < 8; ++ii) {
    if (ii < 7) stage(cur ^ 1, icbase + ii + 1);
    const u16* Qsh = &lds[cur][0][0];
    const u16* Qsl = &lds[cur][1][0];
    #pragma unroll
    for (int it2 = 0; it2 < 2; ++it2) {
      f32x16 s = fz16;
      const int qrow = it2 * 32 + il;
      #pragma unroll
      for (int ks = 0; ks < 4; ++ks) {
        const int ch = ((ks * 2 + hi) ^ (qrow & 7)) * 8;   // swizzled read
        s = mfma32(kah[ks], frag(&Qsh[qrow * 64 + ch]), s);
        s = mfma32(kah[ks], frag(&Qsl[qrow * 64 + ch]), s);
      }
      #pragma unroll
      for (int r = 0; r < 16; ++r) lsum[r] += __expf(s[r]);
    }
    __syncthreads();
    cur ^= 1;
  }

  #pragma unroll
  for (int r = 0; r < 16; ++r) {
    float v = lsum[r];
    v += __shfl_xor(v, 1);  v += __shfl_xor(v, 2);
    v += __shfl_xor(v, 4);  v += __shfl_xor(v, 8);
    v += __shfl_xor(v, 16);
    if (il == 0) {
      const int j = j0 + w * 32 + (r & 3) + 8 * (r >> 2) + 4 * hi;
      atomicAdd(&L[(size_t)bh * 2048 + j], v);
    }
  }
}

// ---------------------------------------------------------------------------
// Scale V^T by 1/l along n:  VT[bh][c][n] *= rcp(L[bh][n])  [round-12 verbatim]
// ---------------------------------------------------------------------------
__global__ __launch_bounds__(256) void k_scale_v(
    u16* __restrict__ wsu, const float* __restrict__ L)
{
  u16* VT = wsu + OFF_VT;
  const size_t vid = (size_t)blockIdx.x * 256 + threadIdx.x;  // 0..524287
  if (vid * 8 >= VT_ELEMS) return;
  const size_t base = vid * 8;
  const int n8 = (int)(vid & 255);
  const int bh = (int)(vid >> 14);
  ushort4 a = *(ushort4*)&VT[base];
  ushort4 b = *(ushort4*)&VT[base + 4];
  const float* Lp = L + (size_t)bh * 2048 + n8 * 8;
  a.x = f2bf(bf2f(a.x) * __builtin_amdgcn_rcpf(Lp[0]));
  a.y = f2bf(bf2f(a.y) * __builtin_amdgcn_rcpf(Lp[1]));
  a.z = f2bf(bf2f(a.z) * __builtin_amdgcn_rcpf(Lp[2]));
  a.w = f2bf(bf2f(a.w) * __builtin_amdgcn_rcpf(Lp[3]));
  b.x = f2bf(bf2f(b.x) * __builtin_amdgcn_rcpf(Lp[4]));
  b.y = f2bf(bf2f(b.y) * __builtin_amdgcn_rcpf(Lp[5]));
  b.z = f2bf(bf2f(b.z) * __builtin_amdgcn_rcpf(Lp[6]));
  b.w = f2bf(bf2f(b.w) * __builtin_amdgcn_rcpf(Lp[7]));
  *(ushort4*)&VT[base] = a;
  *(ushort4*)&VT[base + 4] = b;
}

// ---------------------------------------------------------------------------
// Pass 2 (4-wave, 2-TERM S, in-register P): AV[i][c] = sum_j exp(S_ij) V'[j][c]
// [round-12 verbatim]
// ---------------------------------------------------------------------------
__global__ __launch_bounds__(256, 2) void k_pass2(u16* __restrict__ wsu)
{
  const int bid = blockIdx.x;                  // 512
  const int swz = (bid & 7) * 64 + (bid >> 3);
  const int itile = swz & 15, bh = swz >> 4;
  const int i0 = itile * 128;
  const u16* Qh = wsu + OFF_QH + (size_t)bh * 131072;
  const u16* Ql = wsu + OFF_QL + (size_t)bh * 131072;
  const u16* Kh = wsu + OFF_KH + (size_t)bh * 131072;
  const u16* VT = wsu + OFF_VT + (size_t)bh * 131072;

  __shared__ __align__(16) u16 lds[2][2][4096];  // [buf][Kh,V][64][64]

  const int tid = threadIdx.x;
  const int w = tid >> 6, l = tid & 63;
  const int il = l & 31, hi = l >> 5;

  bf16x8 qbh[4], qbl[4];                       // stationary Q B-frags
  {
    const int irow = i0 + w * 32 + il;
    #pragma unroll
    for (int ks = 0; ks < 4; ++ks) {
      const size_t o = (size_t)irow * 64 + ks * 16 + hi * 8;
      qbh[ks] = frag(&Qh[o]);
      qbl[ks] = frag(&Ql[o]);
    }
  }

  auto stage = [&](int buf, int jc) {
    const int j0 = jc * 64;
    #pragma unroll
    for (int it = 0; it < 4; ++it) {
      const int c = tid + it * 256;            // 0..1023
      const int plane = c >> 9, cc = c & 511;
      const int r = cc >> 3, cl = cc & 7;
      const int sw8 = (cl ^ (r & 7)) * 8;
      const u16* src = plane == 0 ? Kh + (size_t)(j0 + r) * 64 + sw8
                                  : VT + (size_t)r * 2048 + j0 + sw8;
      gload16(src, &lds[buf][0][0] + (size_t)c * 8);
    }
  };

  const f32x16 fz16 = {0,0,0,0,0,0,0,0,0,0,0,0,0,0,0,0};
  f32x16 acc[2]; acc[0] = fz16; acc[1] = fz16;

  stage(0, 0);
  __syncthreads();
  int cur = 0;
  for (int jc = 0; jc < 32; ++jc) {
    if (jc < 31) stage(cur ^ 1, jc + 1);
    const u16* Ksh = &lds[cur][0][0];
    const u16* Vs  = &lds[cur][1][0];
    #pragma unroll
    for (int jt = 0; jt < 2; ++jt) {
      f32x16 s = fz16;
      const int jrow = jt * 32 + il;
      #pragma unroll
      for (int ks = 0; ks < 4; ++ks) {
        const int ch = ((ks * 2 + hi) ^ (jrow & 7)) * 8;
        bf16x8 ka = frag(&Ksh[jrow * 64 + ch]);
        s = mfma32(ka, qbh[ks], s);
        s = mfma32(ka, qbl[ks], s);
      }
      float p[16];
      #pragma unroll
      for (int r = 0; r < 16; ++r) p[r] = __expf(s[r]);
      u32 a0 = cvtpk(p[0],  p[1]),  b0 = cvtpk(p[4],  p[5]);
      u32 a1 = cvtpk(p[2],  p[3]),  b1 = cvtpk(p[6],  p[7]);
      u32 a2 = cvtpk(p[8],  p[9]),  b2 = cvtpk(p[12], p[13]);
      u32 a3 = cvtpk(p[10], p[11]), b3 = cvtpk(p[14], p[15]);
      pswap(a0, b0); pswap(a1, b1); pswap(a2, b2); pswap(a3, b3);
      u32x4 pw0 = {a0, a1, b0, b1};            // k = j 0..15 of this jt
      u32x4 pw1 = {a2, a3, b2, b3};            // k = j 16..31
      bf16x8 pa0 = __builtin_bit_cast(bf16x8, pw0);
      bf16x8 pa1 = __builtin_bit_cast(bf16x8, pw1);
      #pragma unroll
      for (int cb = 0; cb < 2; ++cb) {
        const int crow = cb * 32 + il;
        const int c0 = ((jt * 4 + 0 + hi) ^ (crow & 7)) * 8;
        const int c1 = ((jt * 4 + 2 + hi) ^ (crow & 7)) * 8;
        bf16x8 vb0 = frag(&Vs[crow * 64 + c0]);
        bf16x8 vb1 = frag(&Vs[crow * 64 + c1]);
        acc[cb] = mfma32(pa0, vb0, acc[cb]);
        acc[cb] = mfma32(pa1, vb1, acc[cb]);
      }
    }
    __syncthreads();
    cur ^= 1;
  }

  u16* AVh = wsu + OFF_AVH;                    // hi only (1-term outproj)
  #pragma unroll
  for (int cb = 0; cb < 2; ++cb)
    #pragma unroll
    for (int r = 0; r < 16; ++r) {
      const int iloc = (r & 3) + 8 * (r >> 2) + 4 * hi;
      const int g = i0 + w * 32 + iloc;
      const int c = cb * 32 + il;
      AVh[((size_t)bh * 2048 + g) * 64 + c] = f2bf(acc[cb][r]);
    }
}

// ---------------------------------------------------------------------------
// Output projection: Out = AVh[4096][1024] . WO  (1-term)
// Grid 256 = 1 block/CU -> double-buffered stage-ahead (R11-validated: dbuf
// is right at 1 block/CU where no co-resident block provides overlap).
// ---------------------------------------------------------------------------
__global__ __launch_bounds__(256, 2) void k_outproj(
    const u16* __restrict__ wsu, float* __restrict__ Out)
{
  const int bx = blockIdx.x;                 // 256 = gm(32) * dn(8)
  const int gm = bx >> 3, dn = bx & 7;       // dn == bid&7: per-XCD WOT strip
  const int g0 = gm * 128, d0 = dn * 128;
  const u16* AVh = wsu + OFF_AVH;
  const u16* WOT = wsu + OFF_WOT;

  __shared__ __align__(16) u16 lds[2][16384];  // [buf][A 128x64 | B 128x64]

  const int tid = threadIdx.x;
  const int w = tid >> 6, l = tid & 63, lr = l & 15, lg = l >> 4;
  const int wm = w >> 1, wn = w & 1;

  auto stage = [&](int buf, int t) {
    const int c0 = t * 64;
    #pragma unroll
    for (int it = 0; it < 8; ++it) {
      const int c = tid + it * 256;          // 0..2047 16B chunks
      const u16* src;
      if (c < 1024) {                        // A: AVh rows g0..+127
        const int r = c >> 3, cl = c & 7;
        src = AVh + (size_t)(g0 + r) * 1024 + c0 + (cl ^ (r & 7)) * 8;
      } else {                               // B: WOT rows d0..+127
        const int cc = c - 1024;
        const int r = cc >> 3, cl = cc & 7;
        src = WOT + (size_t)(d0 + r) * 1024 + c0 + (cl ^ (r & 7)) * 8;
      }
      gload16(src, &lds[buf][0] + (size_t)c * 8);
    }
  };

  const f32x4 fz = {0.f, 0.f, 0.f, 0.f};
  f32x4 acc[4][4];
  for (int i = 0; i < 4; ++i) for (int j = 0; j < 4; ++j) acc[i][j] = fz;

  stage(0, 0);
  __syncthreads();
  int cur = 0;
  for (int t = 0; t < 16; ++t) {
    if (t < 15) stage(cur ^ 1, t + 1);
    const u16* As = &lds[cur][0];
    const u16* Bs = &lds[cur][8192];
    #pragma unroll
    for (int ks = 0; ks < 2; ++ks) {
      bf16x8 a[4], b[4];
      #pragma unroll
      for (int mf = 0; mf < 4; ++mf) {
        const int row = wm * 64 + mf * 16 + lr;
        a[mf] = frag(As + row * 64 + ((ks * 4 + lg) ^ (row & 7)) * 8);
      }
      #pragma unroll
      for (int nf = 0; nf < 4; ++nf) {
        const int row = wn * 64 + nf * 16 + lr;
        b[nf] = frag(Bs + row * 64 + ((ks * 4 + lg) ^ (row & 7)) * 8);
      }
      #pragma unroll
      for (int nf = 0; nf < 4; ++nf)
        #pragma unroll
        for (int mf = 0; mf < 4; ++mf)
          acc[mf][nf] = mfma16(a[mf], b[nf], acc[mf][nf]);
    }
    __syncthreads();
    cur ^= 1;
  }
  #pragma unroll
  for (int mf = 0; mf < 4; ++mf)
    #pragma unroll
    for (int nf = 0; nf < 4; ++nf)
      #pragma unroll
      for (int r = 0; r < 4; ++r) {
        const int g = g0 + wm * 64 + mf * 16 + lg * 4 + r;
        const int d = d0 + wn * 64 + nf * 16 + lr;
        Out[(size_t)g * 1024 + d] = acc[mf][nf][r];
      }
}

} // anonymous namespace

extern "C" void kernel_launch(void* const* d_in, const int* in_sizes, int n_in,
                              void* d_out, int out_size, void* d_ws, size_t ws_size,
                              hipStream_t stream) {
  const float* X  = (const float*)d_in[0];
  const float* Wq = (const float*)d_in[1];
  const float* Wk = (const float*)d_in[2];
  const float* Wv = (const float*)d_in[3];
  const float* Wo = (const float*)d_in[4];
  float* out = (float*)d_out;
  u16* wsu = (u16*)d_ws;
  float* L = (float*)(wsu + OFF_L);

  k_prep_x  <<<4096, 256, 0, stream>>>(X, wsu);
  k_prep_w  <<<1024, 256, 0, stream>>>(Wq, Wk, Wv, Wo, wsu);
  k_projg   <<<768,  256, 0, stream>>>(wsu);
  k_pass1   <<<2048, 256, 0, stream>>>(wsu, L);
  k_scale_v <<<2048, 256, 0, stream>>>(wsu, L);
  k_pass2   <<<512,  256, 0, stream>>>(wsu);
  k_outproj <<<256,  256, 0, stream>>>(wsu, out);
}

// Round 15
// 193.540 us; speedup vs baseline: 1.0436x; 1.0216x over previous
//
#include <hip/hip_runtime.h>
#include <math.h>

namespace {

typedef unsigned short u16;
typedef unsigned int   u32;
typedef __bf16 bf16x8 __attribute__((ext_vector_type(8)));
typedef float  f32x4  __attribute__((ext_vector_type(4)));
typedef float  f32x16 __attribute__((ext_vector_type(16)));
typedef u32    u32x4  __attribute__((ext_vector_type(4)));

// ---- workspace layout (u16 element offsets) --------------------------------
constexpr size_t OFF_XH  = 0;          // [4096][1024] bf16 hi of X (dead after proj)
constexpr size_t OFF_WH  = 4194304;    // [3072 j=qkv*1024+h*64+k'][1024 d] hi
constexpr size_t OFF_WL  = 7340032;    //                                   lo
constexpr size_t OFF_QH  = 10485760;   // [32 bh][2048][64]
constexpr size_t OFF_QL  = 14680064;   // [32 bh][2048][64]
constexpr size_t OFF_KH  = 18874368;   // [32 bh][2048][64]
constexpr size_t OFF_VT  = 23068672;   // [32 bh][64][2048]
constexpr size_t OFF_WOT = 27262976;   // [1024 d'][1024 c]
constexpr size_t OFF_L   = 28311552;   // f32[65536] raw column sums (131072 u16)
constexpr size_t OFF_AVH = 0;          // aliases XH (dead after proj)
// end = 28,442,624 u16 = 56.9 MB  (< 65.3 MB proven safe)

constexpr size_t VT_ELEMS = (size_t)32 * 64 * 2048;       // 4,194,304

__device__ __forceinline__ u16 f2bf(float x) {            // RNE fp32 -> bf16
  union { float f; unsigned u; } v; v.f = x;
  unsigned r = v.u + 0x7FFFu + ((v.u >> 16) & 1u);
  return (u16)(r >> 16);
}
__device__ __forceinline__ float bf2f(u16 b) {
  union { unsigned u; float f; } v; v.u = (unsigned)b << 16; return v.f;
}
__device__ __forceinline__ bf16x8 frag(const u16* p) {
  return *reinterpret_cast<const bf16x8*>(p);
}
__device__ __forceinline__ f32x4 mfma16(bf16x8 a, bf16x8 b, f32x4 c) {
  return __builtin_amdgcn_mfma_f32_16x16x32_bf16(a, b, c, 0, 0, 0);
}
__device__ __forceinline__ f32x16 mfma32(bf16x8 a, bf16x8 b, f32x16 c) {
  return __builtin_amdgcn_mfma_f32_32x32x16_bf16(a, b, c, 0, 0, 0);
}
__device__ __forceinline__ void gload16(const void* g, void* l) {
  __builtin_amdgcn_global_load_lds(
      (const __attribute__((address_space(1))) u32*)g,
      (__attribute__((address_space(3))) u32*)l, 16, 0, 0);
}
__device__ __forceinline__ u32 cvtpk(float lo, float hi) {
  u32 r;
  asm("v_cvt_pk_bf16_f32 %0, %1, %2" : "=v"(r) : "v"(lo), "v"(hi));
  return r;
}
__device__ __forceinline__ void pswap(u32& a, u32& b) {
  asm("v_permlane32_swap_b32 %0, %1" : "+v"(a), "+v"(b));
}

// ---------------------------------------------------------------------------
// Prep X: X f32 -> Xh bf16 (hi only); blocks <64 also zero the L accumulator.
// ---------------------------------------------------------------------------
__global__ __launch_bounds__(256) void k_prep_x(
    const float* __restrict__ X, u16* __restrict__ wsu)
{
  u16* Xh = wsu + OFF_XH;
  const size_t i = ((size_t)blockIdx.x * 256 + threadIdx.x) * 4;  // 4096 blocks
  const float4 v = *(const float4*)&X[i];
  ushort4 hh;
  hh.x = f2bf(v.x); hh.y = f2bf(v.y); hh.z = f2bf(v.z); hh.w = f2bf(v.w);
  *(ushort4*)&Xh[i] = hh;
  if (blockIdx.x < 64) {                       // zero L: 64*256*4 = 65536 f32
    float* L = (float*)(wsu + OFF_L);
    const size_t li = ((size_t)blockIdx.x * 256 + threadIdx.x) * 4;
    *(float4*)&L[li] = make_float4(0.f, 0.f, 0.f, 0.f);
  }
}

// ---------------------------------------------------------------------------
// Prep weights: bx<768 -> transpose+hi/lo split W_{q,k,v} into WALL[j][d];
// bx>=768 -> transpose W_O into WOT[d'][c].
// ---------------------------------------------------------------------------
__global__ __launch_bounds__(256) void k_prep_w(
    const float* __restrict__ Wq, const float* __restrict__ Wk,
    const float* __restrict__ Wv, const float* __restrict__ Wo,
    u16* __restrict__ wsu)
{
  const int bx = blockIdx.x;                 // 1024
  const int tid = threadIdx.x;
  __shared__ float T[64][65];
  if (bx < 768) {                            // 768 = qkv(3)*h(16)*dchunk(16)
    const int qkv = bx >> 8, h = (bx >> 4) & 15, dc = bx & 15;
    const float* W = qkv == 0 ? Wq : qkv == 1 ? Wk : Wv;
    const int d0 = dc * 64;
    for (int l = 0; l < 16; ++l) {
      int idx = tid + l * 256; int r = idx >> 6, c = idx & 63;  // r=d, c=k'
      T[r][c] = W[((size_t)h * 1024 + d0 + r) * 64 + c];
    }
    __syncthreads();
    u16* Wh = wsu + OFF_WH;
    u16* Wl = wsu + OFF_WL;
    for (int l = 0; l < 16; ++l) {
      int idx = tid + l * 256; int r = idx >> 6, c = idx & 63;  // r=k', c=d
      float v = T[c][r];
      u16 hi = f2bf(v);
      size_t o = (size_t)((qkv * 16 + h) * 64 + r) * 1024 + d0 + c;
      Wh[o] = hi;
      Wl[o] = f2bf(v - bf2f(hi));
    }
  } else {                                   // 256 = cchunk(16)*dchunk(16)
    const int b2 = bx - 768;
    const int c0 = (b2 >> 4) * 64, dd0 = (b2 & 15) * 64;
    for (int l = 0; l < 16; ++l) {
      int idx = tid + l * 256; int r = idx >> 6, c = idx & 63;
      T[r][c] = Wo[(size_t)(c0 + r) * 1024 + dd0 + c];
    }
    __syncthreads();
    u16* WOT = wsu + OFF_WOT;
    for (int l = 0; l < 16; ++l) {
      int idx = tid + l * 256; int r = idx >> 6, c = idx & 63;
      WOT[(size_t)(dd0 + r) * 1024 + c0 + c] = f2bf(T[c][r]);
    }
  }
}

// ---------------------------------------------------------------------------
// Fused QKV projection: C[4096][3072] = Xh . (Wh+Wl), 2-term split.
// 128x128 tile.  Per d0-iteration stage A ONCE + BOTH W planes (48 KB LDS:
// A|Bh|Bl), then two sequential plane-passes -> mfma sequence bitwise
// identical to the R12/R13 t-even/t-odd order, with half the barriers and
// 25% fewer staging issues.  XOR-swizzled LDS (conflicts 0, verified).
// Grid 768 = 8 XCD x (3 ct x 32 mt) column-ownership; 3 blocks/CU (LDS 48KB).
// ---------------------------------------------------------------------------
__global__ __launch_bounds__(256, 2) void k_projg(u16* __restrict__ wsu)
{
  const int bid = blockIdx.x;                // 768
  const int xcd = bid & 7, local = bid >> 3; // local 0..95
  const int ct = xcd * 3 + local % 3;        // 24 col-tiles of 128
  const int mt = local / 3;                  // 32 row-tiles of 128
  const int gm0 = mt * 128;
  const int j0 = ct * 128;                   // row in WALL
  const int qkv = ct >> 3;

  const u16* XH = wsu + OFF_XH;
  const u16* WH = wsu + OFF_WH;
  const u16* WL = wsu + OFF_WL;

  __shared__ __align__(16) u16 lds[24576];   // A 128x64 | Bh 128x64 | Bl (48 KB)

  const int tid = threadIdx.x;
  const int w = tid >> 6, l = tid & 63, lr = l & 15, lg = l >> 4;
  const int wm = w >> 1, wn = w & 1;

  const f32x4 fz = {0.f, 0.f, 0.f, 0.f};
  f32x4 acc[4][4];
  for (int i = 0; i < 4; ++i) for (int j = 0; j < 4; ++j) acc[i][j] = fz;

  for (int t = 0; t < 16; ++t) {
    const int d0 = t * 64;
    __syncthreads();                         // prev-tile readers done
    #pragma unroll
    for (int it = 0; it < 12; ++it) {
      const int c = tid + it * 256;          // 0..3071 16B chunks
      const u16* src;
      if (c < 1024) {                        // A: X rows gm0..+127
        const int r = c >> 3, cl = c & 7;
        src = XH + (size_t)(gm0 + r) * 1024 + d0 + (cl ^ (r & 7)) * 8;
      } else if (c < 2048) {                 // Bh: WH rows j0..+127
        const int cc = c - 1024;
        const int r = cc >> 3, cl = cc & 7;
        src = WH + (size_t)(j0 + r) * 1024 + d0 + (cl ^ (r & 7)) * 8;
      } else {                               // Bl: WL rows j0..+127
        const int cc = c - 2048;
        const int r = cc >> 3, cl = cc & 7;
        src = WL + (size_t)(j0 + r) * 1024 + d0 + (cl ^ (r & 7)) * 8;
      }
      gload16(src, lds + (size_t)c * 8);
    }
    __syncthreads();                         // loads landed (vmcnt drain)

    const u16* As = lds;
    #pragma unroll
    for (int pl = 0; pl < 2; ++pl) {         // plane pass: Wh then Wl
      const u16* Bs = lds + 8192 + pl * 8192;
      #pragma unroll
      for (int ks = 0; ks < 2; ++ks) {
        bf16x8 a[4], b[4];
        #pragma unroll
        for (int mf = 0; mf < 4; ++mf) {
          const int row = wm * 64 + mf * 16 + lr;
          a[mf] = frag(As + row * 64 + ((ks * 4 + lg) ^ (row & 7)) * 8);
        }
        #pragma unroll
        for (int nf = 0; nf < 4; ++nf) {
          const int row = wn * 64 + nf * 16 + lr;
          b[nf] = frag(Bs + row * 64 + ((ks * 4 + lg) ^ (row & 7)) * 8);
        }
        #pragma unroll
        for (int nf = 0; nf < 4; ++nf)
          #pragma unroll
          for (int mf = 0; mf < 4; ++mf)
            acc[mf][nf] = mfma16(a[mf], b[nf], acc[mf][nf]);
      }
    }
  }

  const int colbase = j0 + wn * 64;          // this wave's 64 cols = ONE head
  const int h = (colbase >> 6) & 15;
  if (qkv == 0) {        // Q: hi/lo planes [bh][n][64]
    u16* Ph = wsu + OFF_QH;
    u16* Pl = wsu + OFF_QL;
    #pragma unroll
    for (int mf = 0; mf < 4; ++mf)
      #pragma unroll
      for (int nf = 0; nf < 4; ++nf)
        #pragma unroll
        for (int r = 0; r < 4; ++r) {
          const float v = acc[mf][nf][r];
          const int gn = gm0 + wm * 64 + mf * 16 + lg * 4 + r;
          const int b = gn >> 11, n = gn & 2047;
          const int kp = nf * 16 + lr;
          const size_t o = ((size_t)(b * 16 + h) * 2048 + n) * 64 + kp;
          const u16 hi = f2bf(v);
          Ph[o] = hi;
          Pl[o] = f2bf(v - bf2f(hi));
        }
  } else if (qkv == 1) { // K: hi only
    u16* Ph = wsu + OFF_KH;
    #pragma unroll
    for (int mf = 0; mf < 4; ++mf)
      #pragma unroll
      for (int nf = 0; nf < 4; ++nf)
        #pragma unroll
        for (int r = 0; r < 4; ++r) {
          const int gn = gm0 + wm * 64 + mf * 16 + lg * 4 + r;
          const int b = gn >> 11, n = gn & 2047;
          const int kp = nf * 16 + lr;
          Ph[((size_t)(b * 16 + h) * 2048 + n) * 64 + kp] = f2bf(acc[mf][nf][r]);
        }
  } else {               // V: transposed store VT[bh][k'][n]
    u16* VT = wsu + OFF_VT;
    #pragma unroll
    for (int mf = 0; mf < 4; ++mf)
      #pragma unroll
      for (int nf = 0; nf < 4; ++nf) {
        const int gn = gm0 + wm * 64 + mf * 16 + lg * 4;
        const int b = gn >> 11, n = gn & 2047;
        const int kp = nf * 16 + lr;
        ushort4 p;
        p.x = f2bf(acc[mf][nf][0]); p.y = f2bf(acc[mf][nf][1]);
        p.z = f2bf(acc[mf][nf][2]); p.w = f2bf(acc[mf][nf][3]);
        *(ushort4*)&VT[((size_t)(b * 16 + h) * 64 + kp) * 2048 + n] = p;
      }
  }
}

// ---------------------------------------------------------------------------
// Pass 1 (i-split x4, 2-TERM: l_j = sum_i exp(Kh_j . (Qh+Ql)_i)), atomicAdd.
// [validated verbatim]
// ---------------------------------------------------------------------------
__global__ __launch_bounds__(256, 2) void k_pass1(
    u16* __restrict__ wsu, float* __restrict__ L)
{
  const int bid = blockIdx.x;                    // 2048
  const int swz = (bid & 7) * 256 + (bid >> 3);
  const int bh = swz >> 6;
  const int jtile = (swz >> 2) & 15;
  const int isl = swz & 3;
  const int j0 = jtile * 128;
  const u16* Qh = wsu + OFF_QH + (size_t)bh * 131072;
  const u16* Ql = wsu + OFF_QL + (size_t)bh * 131072;
  const u16* Kh = wsu + OFF_KH + (size_t)bh * 131072;

  __shared__ __align__(16) u16 lds[2][2][4096];   // [buf][Qhi,Qlo][64][64]

  const int tid = threadIdx.x;
  const int w = tid >> 6, l = tid & 63;
  const int il = l & 31, hi = l >> 5;

  bf16x8 kah[4];                                 // stationary K A-frags
  {
    const int jrow = j0 + w * 32 + il;
    #pragma unroll
    for (int ks = 0; ks < 4; ++ks)
      kah[ks] = frag(&Kh[(size_t)jrow * 64 + ks * 16 + hi * 8]);
  }

  auto stage = [&](int buf, int ic) {
    const int i0 = ic * 64;
    #pragma unroll
    for (int it = 0; it < 4; ++it) {
      const int c = tid + it * 256;              // 0..1023
      const int plane = c >> 9, cc = c & 511;
      const int r = cc >> 3, cl = cc & 7;
      const int sw8 = (cl ^ (r & 7)) * 8;        // inverse-swizzled source
      const u16* src = (plane ? Ql : Qh) + (size_t)(i0 + r) * 64 + sw8;
      gload16(src, &lds[buf][0][0] + (size_t)c * 8);
    }
  };

  const f32x16 fz16 = {0,0,0,0,0,0,0,0,0,0,0,0,0,0,0,0};
  float lsum[16] = {};
  const int icbase = isl * 8;

  stage(0, icbase);
  __syncthreads();
  int cur = 0;
  for (int ii = 0; ii < 8; ++ii) {
    if (ii < 7) stage(cur ^ 1, icbase + ii + 1);
    const u16* Qsh = &lds[cur][0][0];
    const u16* Qsl = &lds[cur][1][0];
    #pragma unroll
    for (int it2 = 0; it2 < 2; ++it2) {
      f32x16 s = fz16;
      const int qrow = it2 * 32 + il;
      #pragma unroll
      for (int ks = 0; ks < 4; ++ks) {
        const int ch = ((ks * 2 + hi) ^ (qrow & 7)) * 8;   // swizzled read
        s = mfma32(kah[ks], frag(&Qsh[qrow * 64 + ch]), s);
        s = mfma32(kah[ks], frag(&Qsl[qrow * 64 + ch]), s);
      }
      #pragma unroll
      for (int r = 0; r < 16; ++r) lsum[r] += __expf(s[r]);
    }
    __syncthreads();
    cur ^= 1;
  }

  #pragma unroll
  for (int r = 0; r < 16; ++r) {
    float v = lsum[r];
    v += __shfl_xor(v, 1);  v += __shfl_xor(v, 2);
    v += __shfl_xor(v, 4);  v += __shfl_xor(v, 8);
    v += __shfl_xor(v, 16);
    if (il == 0) {
      const int j = j0 + w * 32 + (r & 3) + 8 * (r >> 2) + 4 * hi;
      atomicAdd(&L[(size_t)bh * 2048 + j], v);
    }
  }
}

// ---------------------------------------------------------------------------
// Scale V^T by 1/l along n:  VT[bh][c][n] *= rcp(L[bh][n])  [validated verbatim]
// ---------------------------------------------------------------------------
__global__ __launch_bounds__(256) void k_scale_v(
    u16* __restrict__ wsu, const float* __restrict__ L)
{
  u16* VT = wsu + OFF_VT;
  const size_t vid = (size_t)blockIdx.x * 256 + threadIdx.x;  // 0..524287
  if (vid * 8 >= VT_ELEMS) return;
  const size_t base = vid * 8;
  const int n8 = (int)(vid & 255);
  const int bh = (int)(vid >> 14);
  ushort4 a = *(ushort4*)&VT[base];
  ushort4 b = *(ushort4*)&VT[base + 4];
  const float* Lp = L + (size_t)bh * 2048 + n8 * 8;
  a.x = f2bf(bf2f(a.x) * __builtin_amdgcn_rcpf(Lp[0]));
  a.y = f2bf(bf2f(a.y) * __builtin_amdgcn_rcpf(Lp[1]));
  a.z = f2bf(bf2f(a.z) * __builtin_amdgcn_rcpf(Lp[2]));
  a.w = f2bf(bf2f(a.w) * __builtin_amdgcn_rcpf(Lp[3]));
  b.x = f2bf(bf2f(b.x) * __builtin_amdgcn_rcpf(Lp[4]));
  b.y = f2bf(bf2f(b.y) * __builtin_amdgcn_rcpf(Lp[5]));
  b.z = f2bf(bf2f(b.z) * __builtin_amdgcn_rcpf(Lp[6]));
  b.w = f2bf(bf2f(b.w) * __builtin_amdgcn_rcpf(Lp[7]));
  *(ushort4*)&VT[base] = a;
  *(ushort4*)&VT[base + 4] = b;
}

// ---------------------------------------------------------------------------
// Pass 2 (4-wave, 2-TERM S, in-register P): AV[i][c] = sum_j exp(S_ij) V'[j][c]
// [R12-validated verbatim, grid 512]
// ---------------------------------------------------------------------------
__global__ __launch_bounds__(256, 2) void k_pass2(u16* __restrict__ wsu)
{
  const int bid = blockIdx.x;                  // 512
  const int swz = (bid & 7) * 64 + (bid >> 3);
  const int itile = swz & 15, bh = swz >> 4;
  const int i0 = itile * 128;
  const u16* Qh = wsu + OFF_QH + (size_t)bh * 131072;
  const u16* Ql = wsu + OFF_QL + (size_t)bh * 131072;
  const u16* Kh = wsu + OFF_KH + (size_t)bh * 131072;
  const u16* VT = wsu + OFF_VT + (size_t)bh * 131072;

  __shared__ __align__(16) u16 lds[2][2][4096];  // [buf][Kh,V][64][64]

  const int tid = threadIdx.x;
  const int w = tid >> 6, l = tid & 63;
  const int il = l & 31, hi = l >> 5;

  bf16x8 qbh[4], qbl[4];                       // stationary Q B-frags
  {
    const int irow = i0 + w * 32 + il;
    #pragma unroll
    for (int ks = 0; ks < 4; ++ks) {
      const size_t o = (size_t)irow * 64 + ks * 16 + hi * 8;
      qbh[ks] = frag(&Qh[o]);
      qbl[ks] = frag(&Ql[o]);
    }
  }

  auto stage = [&](int buf, int jc) {
    const int j0 = jc * 64;
    #pragma unroll
    for (int it = 0; it < 4; ++it) {
      const int c = tid + it * 256;            // 0..1023
      const int plane = c >> 9, cc = c & 511;
      const int r = cc >> 3, cl = cc & 7;
      const int sw8 = (cl ^ (r & 7)) * 8;
      const u16* src = plane == 0 ? Kh + (size_t)(j0 + r) * 64 + sw8
                                  : VT + (size_t)r * 2048 + j0 + sw8;
      gload16(src, &lds[buf][0][0] + (size_t)c * 8);
    }
  };

  const f32x16 fz16 = {0,0,0,0,0,0,0,0,0,0,0,0,0,0,0,0};
  f32x16 acc[2]; acc[0] = fz16; acc[1] = fz16;

  stage(0, 0);
  __syncthreads();
  int cur = 0;
  for (int jc = 0; jc < 32; ++jc) {
    if (jc < 31) stage(cur ^ 1, jc + 1);
    const u16* Ksh = &lds[cur][0][0];
    const u16* Vs  = &lds[cur][1][0];
    #pragma unroll
    for (int jt = 0; jt < 2; ++jt) {
      f32x16 s = fz16;
      const int jrow = jt * 32 + il;
      #pragma unroll
      for (int ks = 0; ks < 4; ++ks) {
        const int ch = ((ks * 2 + hi) ^ (jrow & 7)) * 8;
        bf16x8 ka = frag(&Ksh[jrow * 64 + ch]);
        s = mfma32(ka, qbh[ks], s);
        s = mfma32(ka, qbl[ks], s);
      }
      float p[16];
      #pragma unroll
      for (int r = 0; r < 16; ++r) p[r] = __expf(s[r]);
      u32 a0 = cvtpk(p[0],  p[1]),  b0 = cvtpk(p[4],  p[5]);
      u32 a1 = cvtpk(p[2],  p[3]),  b1 = cvtpk(p[6],  p[7]);
      u32 a2 = cvtpk(p[8],  p[9]),  b2 = cvtpk(p[12], p[13]);
      u32 a3 = cvtpk(p[10], p[11]), b3 = cvtpk(p[14], p[15]);
      pswap(a0, b0); pswap(a1, b1); pswap(a2, b2); pswap(a3, b3);
      u32x4 pw0 = {a0, a1, b0, b1};            // k = j 0..15 of this jt
      u32x4 pw1 = {a2, a3, b2, b3};            // k = j 16..31
      bf16x8 pa0 = __builtin_bit_cast(bf16x8, pw0);
      bf16x8 pa1 = __builtin_bit_cast(bf16x8, pw1);
      #pragma unroll
      for (int cb = 0; cb < 2; ++cb) {
        const int crow = cb * 32 + il;
        const int c0 = ((jt * 4 + 0 + hi) ^ (crow & 7)) * 8;
        const int c1 = ((jt * 4 + 2 + hi) ^ (crow & 7)) * 8;
        bf16x8 vb0 = frag(&Vs[crow * 64 + c0]);
        bf16x8 vb1 = frag(&Vs[crow * 64 + c1]);
        acc[cb] = mfma32(pa0, vb0, acc[cb]);
        acc[cb] = mfma32(pa1, vb1, acc[cb]);
      }
    }
    __syncthreads();
    cur ^= 1;
  }

  u16* AVh = wsu + OFF_AVH;                    // hi only (1-term outproj)
  #pragma unroll
  for (int cb = 0; cb < 2; ++cb)
    #pragma unroll
    for (int r = 0; r < 16; ++r) {
      const int iloc = (r & 3) + 8 * (r >> 2) + 4 * hi;
      const int g = i0 + w * 32 + iloc;
      const int c = cb * 32 + il;
      AVh[((size_t)bh * 2048 + g) * 64 + c] = f2bf(acc[cb][r]);
    }
}

// ---------------------------------------------------------------------------
// Output projection: Out = AVh . WO  (1-term)  [R13-validated verbatim: dbuf]
// ---------------------------------------------------------------------------
__global__ __launch_bounds__(256, 2) void k_outproj(
    const u16* __restrict__ wsu, float* __restrict__ Out)
{
  const int bx = blockIdx.x;                 // 256 = gm(32) * dn(8)
  const int gm = bx >> 3, dn = bx & 7;       // dn == bid&7: per-XCD WOT strip
  const int g0 = gm * 128, d0 = dn * 128;
  const u16* AVh = wsu + OFF_AVH;
  const u16* WOT = wsu + OFF_WOT;

  __shared__ __align__(16) u16 lds[2][16384];  // [buf][A 128x64 | B 128x64]

  const int tid = threadIdx.x;
  const int w = tid >> 6, l = tid & 63, lr = l & 15, lg = l >> 4;
  const int wm = w >> 1, wn = w & 1;

  auto stage = [&](int buf, int t) {
    const int c0 = t * 64;
    #pragma unroll
    for (int it = 0; it < 8; ++it) {
      const int c = tid + it * 256;          // 0..2047 16B chunks
      const u16* src;
      if (c < 1024) {                        // A: AVh rows g0..+127
        const int r = c >> 3, cl = c & 7;
        src = AVh + (size_t)(g0 + r) * 1024 + c0 + (cl ^ (r & 7)) * 8;
      } else {                               // B: WOT rows d0..+127
        const int cc = c - 1024;
        const int r = cc >> 3, cl = cc & 7;
        src = WOT + (size_t)(d0 + r) * 1024 + c0 + (cl ^ (r & 7)) * 8;
      }
      gload16(src, &lds[buf][0] + (size_t)c * 8);
    }
  };

  const f32x4 fz = {0.f, 0.f, 0.f, 0.f};
  f32x4 acc[4][4];
  for (int i = 0; i < 4; ++i) for (int j = 0; j < 4; ++j) acc[i][j] = fz;

  stage(0, 0);
  __syncthreads();
  int cur = 0;
  for (int t = 0; t < 16; ++t) {
    if (t < 15) stage(cur ^ 1, t + 1);
    const u16* As = &lds[cur][0];
    const u16* Bs = &lds[cur][8192];
    #pragma unroll
    for (int ks = 0; ks < 2; ++ks) {
      bf16x8 a[4], b[4];
      #pragma unroll
      for (int mf = 0; mf < 4; ++mf) {
        const int row = wm * 64 + mf * 16 + lr;
        a[mf] = frag(As + row * 64 + ((ks * 4 + lg) ^ (row & 7)) * 8);
      }
      #pragma unroll
      for (int nf = 0; nf < 4; ++nf) {
        const int row = wn * 64 + nf * 16 + lr;
        b[nf] = frag(Bs + row * 64 + ((ks * 4 + lg) ^ (row & 7)) * 8);
      }
      #pragma unroll
      for (int nf = 0; nf < 4; ++nf)
        #pragma unroll
        for (int mf = 0; mf < 4; ++mf)
          acc[mf][nf] = mfma16(a[mf], b[nf], acc[mf][nf]);
    }
    __syncthreads();
    cur ^= 1;
  }
  #pragma unroll
  for (int mf = 0; mf < 4; ++mf)
    #pragma unroll
    for (int nf = 0; nf < 4; ++nf)
      #pragma unroll
      for (int r = 0; r < 4; ++r) {
        const int g = g0 + wm * 64 + mf * 16 + lg * 4 + r;
        const int d = d0 + wn * 64 + nf * 16 + lr;
        Out[(size_t)g * 1024 + d] = acc[mf][nf][r];
      }
}

} // anonymous namespace

extern "C" void kernel_launch(void* const* d_in, const int* in_sizes, int n_in,
                              void* d_out, int out_size, void* d_ws, size_t ws_size,
                              hipStream_t stream) {
  const float* X  = (const float*)d_in[0];
  const float* Wq = (const float*)d_in[1];
  const float* Wk = (const float*)d_in[2];
  const float* Wv = (const float*)d_in[3];
  const float* Wo = (const float*)d_in[4];
  float* out = (float*)d_out;
  u16* wsu = (u16*)d_ws;
  float* L = (float*)(wsu + OFF_L);

  k_prep_x  <<<4096, 256, 0, stream>>>(X, wsu);
  k_prep_w  <<<1024, 256, 0, stream>>>(Wq, Wk, Wv, Wo, wsu);
  k_projg   <<<768,  256, 0, stream>>>(wsu);
  k_pass1   <<<2048, 256, 0, stream>>>(wsu, L);
  k_scale_v <<<2048, 256, 0, stream>>>(wsu, L);
  k_pass2   <<<512,  256, 0, stream>>>(wsu);
  k_outproj <<<256,  256, 0, stream>>>(wsu, out);
}